// Round 16
// baseline (41088.641 us; speedup 1.0000x reference)
//
#include <hip/hip_runtime.h>
#include <stdint.h>

// AutoregressiveRAM: 4095 serial steps of an 8192-neuron weightless NN.
// R16 = BARRIER-FREE DATAFLOW. Each thread's neuron taps exactly 10 of the
// 256 state words (static, in registers). Instead of the champion pipeline
// {240-thread poll -> barrier -> LDS redistribute -> gather -> barrier},
// every thread fetches ITS OWN tapped words directly from the tagged
// mailbox: issue all 10 loads in parallel (compiler-managed waitcnt ->
// sound; nothing abandoned in flight), check all 10 tags, re-issue all on
// any miss (~2 rounds). Waves proceed the moment their own taps are
// visible. NO __syncthreads, NO __shared__ at all; pos-bit taps (cc>=8192)
// are computed in-register from i.
//
// Correctness without barriers:
//  - Tag travels WITH data (8B word: data lo32, tag=s+1 hi32). Stale or
//    destroyed generations can never match the awaited tag: any protocol
//    violation becomes a spin-timeout -> wrong (poisoned) output -> VISIBLE
//    test failure, never silent corruption.
//  - Overwrite safety via SLOTS=8: publishing state i (slot i&7) destroys
//    state i-8, harmful only if some wave still needs it, i.e. inter-wave
//    drift >= 7. Drift is bounded by the tap dependency graph: each wave
//    taps ~125.6 of its 127 siblings (miss prob 0.0067 per pair); 1-hop
//    gives drift<=2 for 99.3% of pairs, 2-hop coverage fails with prob
//    ~1e-101 on this fixed random input -> drift<=3 with astronomical
//    margin. Violation = visible timeout, not corruption.
//  - Re-read stability: a word matching tag i is immutable until state i+7
//    publish (drift-excluded) -> re-issued loads of matched words are safe.
// Replay-safe: mailbox memset each call; tags strictly positive.

#define BITS   8192
#define NBT    10
#define NBLK   16
#define TPB    512
#define NPB    (BITS / NBLK)   // 512 neurons per block (1 per thread)
#define SWORDS 256             // 8192 state bits / 32
#define WPB    (NPB / 32)      // 16 state words owned per block
#define SLOTS  8               // mailbox generations (drift guard)
#define FUSE   1024            // poll rounds per step; expiry -> visible fail

typedef unsigned long long u64;
typedef uint32_t u32;

__global__ void pack_kernel(const float* __restrict__ tm, u32* __restrict__ packed) {
    // 8192*1024 floats -> 262144 packed u32 words. One float per thread.
    int tid = blockIdx.x * blockDim.x + threadIdx.x;
    float v = tm[tid];
    u64 m = __ballot(v > 0.5f);
    int lane = tid & 63;
    if ((lane & 31) == 0) {
        packed[tid >> 5] = (lane == 0) ? (u32)m : (u32)(m >> 32);
    }
}

__global__ __launch_bounds__(TPB) void ram_step_kernel(
    const int* __restrict__ conn,        // [8192][10]
    const float* __restrict__ init_mem,  // [8192][16]
    const u32* __restrict__ packedT,     // [8192][32]
    u64* __restrict__ pairs,             // [SLOTS][SWORDS] (data lo, tag hi)
    float* __restrict__ out,             // [length][8192]
    int length)
{
    const int b = blockIdx.x;
    const int t = threadIdx.x;
    const int lane = t & 63;
    const int n = b * NPB + t;           // this thread's neuron

    // Connections are static: registers for the whole run.
    int c[NBT];
#pragma unroll
    for (int j = 0; j < NBT; ++j) c[j] = conn[n * NBT + j];

    // ---- step 0: pos bits of 0 are all zero -> addr 0 -> initial_memory[:,0]
    float v0 = init_mem[n << 4];
    out[n] = v0;
    int bit = (v0 > 0.5f) ? 1 : 0;
    u64 m = __ballot(bit);
    const int gw = b * WPB + (t >> 6) * 2;  // this wave's state-word base
    if (lane == 0) {
        const u64 tag = 1ull << 32;         // tag(state s) = s+1; state 0 -> slot 0
        __hip_atomic_store(&pairs[gw],     tag | (u32)m,
                           __ATOMIC_RELAXED, __HIP_MEMORY_SCOPE_AGENT);
        __hip_atomic_store(&pairs[gw + 1], tag | (u32)(m >> 32),
                           __ATOMIC_RELAXED, __HIP_MEMORY_SCOPE_AGENT);
    }

    for (int i = 1; i < length; ++i) {
        u64* sl = pairs + (size_t)((i - 1) & (SLOTS - 1)) * SWORDS;
        const u32 want = (u32)i;            // tag of state i-1

        // fetch own taps: all ~10 loads in flight per round, full re-issue on
        // any miss. Static unroll -> no scratch (rule #20); compiler inserts
        // progressive vmcnt before each check (sound).
        u64 v[NBT];
#pragma unroll
        for (int j = 0; j < NBT; ++j) v[j] = 0;
        int fuse = 0;
        bool ok;
        do {
            ok = true;
#pragma unroll
            for (int j = 0; j < NBT; ++j) {
                if (c[j] < BITS)
                    v[j] = __hip_atomic_load(&sl[c[j] >> 5], __ATOMIC_RELAXED,
                                             __HIP_MEMORY_SCOPE_AGENT);
            }
#pragma unroll
            for (int j = 0; j < NBT; ++j) {
                if (c[j] < BITS)
                    ok = ok & ((u32)(v[j] >> 32) == want);
            }
        } while (!ok && ++fuse < FUSE);

        // gather 10 bits -> 10-bit address (conn[0] is MSB); pos taps from i
        u32 addr = 0;
#pragma unroll
        for (int j = 0; j < NBT; ++j) {
            int cc = c[j];
            u32 bj = (cc < BITS) ? ((((u32)v[j]) >> (cc & 31)) & 1u)
                                 : (u32)((i >> (3 - (cc - BITS))) & 1);
            addr = (addr << 1) | bj;
        }
        u32 pw = packedT[(n << 5) + (addr >> 5)];
        bit = (pw >> (addr & 31)) & 1;
        out[(size_t)i * BITS + n] = (float)bit;

        // publish own 2 words of state i (champion order: after out-store)
        m = __ballot(bit);
        if (lane == 0) {
            const u64 tag = ((u64)(i + 1)) << 32;
            u64* ps = pairs + (size_t)(i & (SLOTS - 1)) * SWORDS + gw;
            __hip_atomic_store(ps,     tag | (u32)m,
                               __ATOMIC_RELAXED, __HIP_MEMORY_SCOPE_AGENT);
            __hip_atomic_store(ps + 1, tag | (u32)(m >> 32),
                               __ATOMIC_RELAXED, __HIP_MEMORY_SCOPE_AGENT);
        }
    }
}

extern "C" void kernel_launch(void* const* d_in, const int* in_sizes, int n_in,
                              void* d_out, int out_size, void* d_ws, size_t ws_size,
                              hipStream_t stream) {
    const float* tm = (const float*)d_in[0];     // transition_memory [8192][1024]
    const float* im = (const float*)d_in[1];     // initial_memory    [8192][16]
    const int*   tc = (const int*)d_in[2];       // transition_connections [8192][10]
    // d_in[3] (initial_connections) is provably unused: pos_bits(0)==0 -> addr 0.
    const int length = out_size / BITS;

    u32* packed = (u32*)d_ws;                              // 1 MB
    u64* pairs  = (u64*)((char*)d_ws + (1 << 20));         // 16 KB (8 slots)

    // Clean mailbox every call/replay (graph-capturable memset node).
    hipMemsetAsync(pairs, 0, SLOTS * SWORDS * sizeof(u64), stream);

    // Pack transition RAM to bits: 8192*1024 floats, 1 thread each.
    pack_kernel<<<dim3((BITS * 1024) / 256), dim3(256), 0, stream>>>(tm, packed);

    // Persistent recurrence kernel: 16 blocks (always co-resident on 256 CUs).
    ram_step_kernel<<<dim3(NBLK), dim3(TPB), 0, stream>>>(
        tc, im, packed, pairs, (float*)d_out, length);
}